// Round 1
// baseline (714.518 us; speedup 1.0000x reference)
//
#include <hip/hip_runtime.h>
#include <math.h>

typedef unsigned short u16;
typedef unsigned int   u32;
typedef __attribute__((ext_vector_type(8))) short bf16x8;          // 8 bf16 = 4 VGPR (MFMA A/B frag)
typedef __attribute__((ext_vector_type(4))) float f32x4;           // MFMA C/D frag
typedef __attribute__((ext_vector_type(4))) unsigned short u16x4;

__device__ __forceinline__ float bf2f(u16 v){ return __uint_as_float(((u32)v) << 16); }
__device__ __forceinline__ u16 f2bf(float f){
  u32 u = __float_as_uint(f);
  return (u16)((u + 0x7fffu + ((u >> 16) & 1u)) >> 16);  // RNE
}
__device__ __forceinline__ float elu1(float x){ return x > 0.f ? x + 1.f : __expf(x); }

// ---------------- cast f32 -> bf16, vectorized x4 ----------------
__global__ __launch_bounds__(256) void k_cast(const float* __restrict__ src, u16* __restrict__ dst, int n4){
  int i = blockIdx.x * 256 + threadIdx.x;
  int stride = gridDim.x * 256;
  for (; i < n4; i += stride){
    float4 v = ((const float4*)src)[i];
    u16x4 o; o.x = f2bf(v.x); o.y = f2bf(v.y); o.z = f2bf(v.z); o.w = f2bf(v.w);
    ((u16x4*)dst)[i] = o;
  }
}

// concat q_b,k_b,v_b -> one 3072-float bias
__global__ void k_cat3(const float* __restrict__ a, const float* __restrict__ b,
                       const float* __restrict__ c, float* __restrict__ dst){
  int i = blockIdx.x * 256 + threadIdx.x;
  dst[i] = i < 1024 ? a[i] : (i < 2048 ? b[i - 1024] : c[i - 2048]);
}

// ---------------- LayerNorm over C=1024: f32 in -> bf16 out ----------------
__global__ __launch_bounds__(256) void k_ln(const float* __restrict__ x, const float* __restrict__ w,
                                            const float* __restrict__ b, u16* __restrict__ out){
  const int t = threadIdx.x;
  const size_t m = blockIdx.x;
  float4 v = ((const float4*)(x + m * 1024))[t];
  float s  = v.x + v.y + v.z + v.w;
  float s2 = v.x*v.x + v.y*v.y + v.z*v.z + v.w*v.w;
  #pragma unroll
  for (int o = 32; o > 0; o >>= 1){ s += __shfl_down(s, o, 64); s2 += __shfl_down(s2, o, 64); }
  __shared__ float red[8];
  if ((t & 63) == 0){ red[t >> 6] = s; red[4 + (t >> 6)] = s2; }
  __syncthreads();
  s  = red[0] + red[1] + red[2] + red[3];
  s2 = red[4] + red[5] + red[6] + red[7];
  float mu  = s * (1.f / 1024.f);
  float inv = rsqrtf(s2 * (1.f / 1024.f) - mu * mu + 1e-5f);
  float4 wv = ((const float4*)w)[t];
  float4 bv = ((const float4*)b)[t];
  u16x4 o;
  o.x = f2bf((v.x - mu) * inv * wv.x + bv.x);
  o.y = f2bf((v.y - mu) * inv * wv.y + bv.y);
  o.z = f2bf((v.z - mu) * inv * wv.z + bv.z);
  o.w = f2bf((v.w - mu) * inv * wv.w + bv.w);
  ((u16x4*)(out + m * 1024))[t] = o;
}

// ---------------- per-token linear attention ----------------
// s[h][h'] = sum_d qe[h,d]*ke[h',d];  out[h,e] = (sum_h' s*v[h',e]) / (sum_h' s[h,h'])
// one wave per token, 4 tokens per block; qkv layout per token: [q(1024) k(1024) v(1024)] bf16
__global__ __launch_bounds__(256) void k_attn(const u16* __restrict__ qkv, u16* __restrict__ out){
  __shared__ float qe[4][16][68];
  __shared__ float ke[4][16][68];
  __shared__ float sm[4][16][20];
  const int w = threadIdx.x >> 6, lane = threadIdx.x & 63;
  const size_t m = (size_t)blockIdx.x * 4 + w;
  const u16* base = qkv + m * 3072;
  #pragma unroll
  for (int i = 0; i < 8; ++i){
    int idx = i * 64 + lane;              // u32 index into 16x64 bf16 tile
    int h = idx >> 5, c2 = (idx & 31) * 2;
    u32 qv = ((const u32*)base)[idx];
    u32 kv = ((const u32*)base)[512 + idx];
    float2 qf, kf;
    qf.x = elu1(bf2f((u16)(qv & 0xffffu))); qf.y = elu1(bf2f((u16)(qv >> 16)));
    kf.x = elu1(bf2f((u16)(kv & 0xffffu))); kf.y = elu1(bf2f((u16)(kv >> 16)));
    *(float2*)&qe[w][h][c2] = qf;
    *(float2*)&ke[w][h][c2] = kf;
  }
  float vr[16];
  #pragma unroll
  for (int h = 0; h < 16; ++h) vr[h] = bf2f(base[2048 + h * 64 + lane]);
  __syncthreads();
  // s: lane handles h = lane>>2, h' in [4*(lane&3), +4)
  const int sh = lane >> 2, jb = lane & 3;
  float sacc[4] = {0.f, 0.f, 0.f, 0.f};
  #pragma unroll
  for (int d4 = 0; d4 < 16; ++d4){
    float4 q4 = *(const float4*)&qe[w][sh][d4 * 4];
    #pragma unroll
    for (int j = 0; j < 4; ++j){
      float4 k4 = *(const float4*)&ke[w][4 * jb + j][d4 * 4];
      sacc[j] += q4.x*k4.x + q4.y*k4.y + q4.z*k4.z + q4.w*k4.w;
    }
  }
  #pragma unroll
  for (int j = 0; j < 4; ++j) sm[w][sh][4 * jb + j] = sacc[j];
  float part = sacc[0] + sacc[1] + sacc[2] + sacc[3];
  part += __shfl_xor(part, 1, 64);
  part += __shfl_xor(part, 2, 64);
  if (jb == 0) sm[w][sh][16] = part;     // qk[h]
  __syncthreads();
  // qkv: lane owns column e = lane
  float acc[16];
  #pragma unroll
  for (int h = 0; h < 16; ++h) acc[h] = 0.f;
  #pragma unroll
  for (int h = 0; h < 16; ++h){
    #pragma unroll
    for (int j4 = 0; j4 < 4; ++j4){
      float4 s4 = *(const float4*)&sm[w][h][j4 * 4];
      acc[h] += s4.x*vr[4*j4] + s4.y*vr[4*j4+1] + s4.z*vr[4*j4+2] + s4.w*vr[4*j4+3];
    }
  }
  u16* ob = out + m * 1024;
  #pragma unroll
  for (int h = 0; h < 16; ++h)
    ob[h * 64 + lane] = f2bf(acc[h] / sm[w][h][16]);
}

// ---------------- bf16 GEMM, C = A(M,K) * W(N,K)^T + bias, 128x128 tile ----------------
// EPI 0: bf16 out          1: f32 out = res + v       2: bf16 out = gelu(v)      3: f32 out += v (in place)
template<int EPI>
__global__ __launch_bounds__(256, 2) void k_gemm(const u16* __restrict__ A, const u16* __restrict__ W,
                                                 const float* __restrict__ bias, const float* __restrict__ res,
                                                 void* __restrict__ outp, int N, int K){
  __shared__ alignas(16) char lds[65536];   // 2 buffers x (A 16KB | B 16KB), BK=64
  const int tid = threadIdx.x;
  const int lane = tid & 63, wv = tid >> 6;
  const int wr = wv >> 1, wc = wv & 1;
  const int g = lane >> 4, l15 = lane & 15;
  const int m0 = blockIdx.x * 128, n0 = blockIdx.y * 128;
  const u16* gA = A + (size_t)m0 * K;
  const u16* gW = W + (size_t)n0 * K;
  const int nt = K >> 6;

  f32x4 acc[4][4];
  #pragma unroll
  for (int i = 0; i < 4; ++i)
    #pragma unroll
    for (int j = 0; j < 4; ++j) acc[i][j] = (f32x4){0.f, 0.f, 0.f, 0.f};

  // stage one 128x64 A-tile + B-tile into buf. LDS dest linear; global source
  // pre-swizzled (chunk ^= row&7) so swizzled ds_reads below are conflict-free.
  auto stage = [&](int buf, int kt){
    const int k0 = kt << 6;
    char* db = lds + buf * 32768;
    #pragma unroll
    for (int i = 0; i < 4; ++i){
      int li = i * 256 + tid;
      int row = li >> 3;
      int ch = (li & 7) ^ (row & 7);
      __builtin_amdgcn_global_load_lds(
        (const __attribute__((address_space(1))) u32*)(gA + (size_t)row * K + k0 + ch * 8),
        (__attribute__((address_space(3))) u32*)(db + i * 4096 + wv * 1024), 16, 0, 0);
    }
    #pragma unroll
    for (int i = 0; i < 4; ++i){
      int li = i * 256 + tid;
      int row = li >> 3;
      int ch = (li & 7) ^ (row & 7);
      __builtin_amdgcn_global_load_lds(
        (const __attribute__((address_space(1))) u32*)(gW + (size_t)row * K + k0 + ch * 8),
        (__attribute__((address_space(3))) u32*)(db + 16384 + i * 4096 + wv * 1024), 16, 0, 0);
    }
  };

  stage(0, 0);
  __syncthreads();        // drains vmcnt (global_load_lds) + barrier
  int cur = 0;
  for (int kt = 0; kt < nt; ++kt){
    if (kt + 1 < nt) stage(cur ^ 1, kt + 1);   // prefetch overlaps compute
    const char* bp = lds + cur * 32768;
    bf16x8 af[2][4], bf[2][4];
    #pragma unroll
    for (int s = 0; s < 2; ++s){
      #pragma unroll
      for (int f = 0; f < 4; ++f){
        int rowA = 64 * wr + 16 * f + l15;
        af[s][f] = *(const bf16x8*)(bp + rowA * 128 + (((4 * s + g) ^ (rowA & 7)) << 4));
        int rowB = 64 * wc + 16 * f + l15;
        bf[s][f] = *(const bf16x8*)(bp + 16384 + rowB * 128 + (((4 * s + g) ^ (rowB & 7)) << 4));
      }
    }
    #pragma unroll
    for (int s = 0; s < 2; ++s)
      #pragma unroll
      for (int mf = 0; mf < 4; ++mf)
        #pragma unroll
        for (int nf = 0; nf < 4; ++nf)
          acc[mf][nf] = __builtin_amdgcn_mfma_f32_16x16x32_bf16(af[s][mf], bf[s][nf], acc[mf][nf], 0, 0, 0);
    __syncthreads();
    cur ^= 1;
  }
  // epilogue: D frag is col = lane&15, row = 4*(lane>>4) + r
  #pragma unroll
  for (int mf = 0; mf < 4; ++mf){
    #pragma unroll
    for (int nf = 0; nf < 4; ++nf){
      int row = m0 + 64 * wr + 16 * mf + 4 * g;
      int col = n0 + 64 * wc + 16 * nf + l15;
      float bcol = bias[col];
      #pragma unroll
      for (int r = 0; r < 4; ++r){
        float v = acc[mf][nf][r] + bcol;
        size_t idx = (size_t)(row + r) * N + col;
        if constexpr (EPI == 0){
          ((u16*)outp)[idx] = f2bf(v);
        } else if constexpr (EPI == 1){
          ((float*)outp)[idx] = res[idx] + v;
        } else if constexpr (EPI == 2){
          ((u16*)outp)[idx] = f2bf(0.5f * v * (1.f + erff(v * 0.70710678118f)));
        } else {
          float* o = (float*)outp; o[idx] = o[idx] + v;
        }
      }
    }
  }
}

extern "C" void kernel_launch(void* const* d_in, const int* in_sizes, int n_in,
                              void* d_out, int out_size, void* d_ws, size_t ws_size,
                              hipStream_t stream){
  (void)in_sizes; (void)n_in; (void)out_size; (void)ws_size;
  const float* x    = (const float*)d_in[0];
  const float* ln1w = (const float*)d_in[1];
  const float* ln1b = (const float*)d_in[2];
  const float* qw   = (const float*)d_in[3];
  const float* qb   = (const float*)d_in[4];
  const float* kw   = (const float*)d_in[5];
  const float* kb   = (const float*)d_in[6];
  const float* vw   = (const float*)d_in[7];
  const float* vb   = (const float*)d_in[8];
  const float* ow   = (const float*)d_in[9];
  const float* ob   = (const float*)d_in[10];
  const float* ln2w = (const float*)d_in[11];
  const float* ln2b = (const float*)d_in[12];
  const float* fcw  = (const float*)d_in[13];
  const float* fcb  = (const float*)d_in[14];
  const float* pw   = (const float*)d_in[15];
  const float* pb   = (const float*)d_in[16];

  char* ws = (char*)d_ws;
  u16*   WQKV = (u16*)(ws + 0);              // [3072][1024] bf16 (q_w|k_w|v_w)
  u16*   WO   = (u16*)(ws + 6291456);        // [1024][1024]
  u16*   WFC  = (u16*)(ws + 8388608);        // [4096][1024]
  u16*   WPR  = (u16*)(ws + 16777216);       // [1024][4096]
  float* BQ   = (float*)(ws + 25165824);     // [3072]
  u16*   XN   = (u16*)(ws + 25178112);       // [16384][1024] bf16 (xn, reused for xn2)
  u16*   QKV  = (u16*)(ws + 58732544);       // [16384][3072] bf16
  u16*   ATT  = (u16*)(ws + 159395840);      // [16384][1024] bf16
  u16*   H    = QKV;                          // [16384][4096] bf16, reuses QKV+ATT region
  float* OUT  = (float*)d_out;               // x1 intermediate, then final output

  // weight casts (fp32 -> bf16)
  k_cast<<<512, 256, 0, stream>>>(qw, WQKV,           262144);
  k_cast<<<512, 256, 0, stream>>>(kw, WQKV + 1048576, 262144);
  k_cast<<<512, 256, 0, stream>>>(vw, WQKV + 2097152, 262144);
  k_cast<<<512, 256, 0, stream>>>(ow, WO,             262144);
  k_cast<<<1024, 256, 0, stream>>>(fcw, WFC,          1048576);
  k_cast<<<1024, 256, 0, stream>>>(pw,  WPR,          1048576);
  k_cat3<<<12, 256, 0, stream>>>(qb, kb, vb, BQ);

  // ln1 -> fused QKV gemm -> per-token attention -> O gemm (+x residual) -> OUT (x1)
  k_ln<<<16384, 256, 0, stream>>>(x, ln1w, ln1b, XN);
  k_gemm<0><<<dim3(128, 24), 256, 0, stream>>>(XN, WQKV, BQ, nullptr, QKV, 3072, 1024);
  k_attn<<<4096, 256, 0, stream>>>(QKV, ATT);
  k_gemm<1><<<dim3(128, 8), 256, 0, stream>>>(ATT, WO, ob, x, OUT, 1024, 1024);

  // ln2 -> FC gemm (+gelu) -> PROJ gemm (+x1 residual, in place on OUT)
  k_ln<<<16384, 256, 0, stream>>>(OUT, ln2w, ln2b, XN);
  k_gemm<2><<<dim3(128, 32), 256, 0, stream>>>(XN, WFC, fcb, nullptr, H, 4096, 1024);
  k_gemm<3><<<dim3(128, 8), 256, 0, stream>>>(H, WPR, pb, nullptr, OUT, 1024, 4096);
}

// Round 2
// 571.637 us; speedup vs baseline: 1.2499x; 1.2499x over previous
//
#include <hip/hip_runtime.h>
#include <math.h>

typedef unsigned short u16;
typedef unsigned int   u32;
typedef __attribute__((ext_vector_type(8))) short bf16x8;          // 8 bf16 = 4 VGPR (MFMA A/B frag)
typedef __attribute__((ext_vector_type(4))) float f32x4;           // MFMA C/D frag
typedef __attribute__((ext_vector_type(4))) unsigned short u16x4;

__device__ __forceinline__ float bf2f(u16 v){ return __uint_as_float(((u32)v) << 16); }
__device__ __forceinline__ u16 f2bf(float f){
  u32 u = __float_as_uint(f);
  return (u16)((u + 0x7fffu + ((u >> 16) & 1u)) >> 16);  // RNE
}
__device__ __forceinline__ float elu1(float x){ return x > 0.f ? x + 1.f : __expf(x); }
__device__ __forceinline__ float gelu_f(float v){
  // tanh-form gelu; |diff vs erf-form| < ~3e-3, well under bf16-scale threshold
  float u = 0.7978845608f * (v + 0.044715f * v * v * v);
  float e = __expf(-2.f * fabsf(u));
  float th = copysignf((1.f - e) / (1.f + e), u);
  return 0.5f * v * (1.f + th);
}

// ---------------- cast f32 -> bf16, vectorized x4 ----------------
__global__ __launch_bounds__(256) void k_cast(const float* __restrict__ src, u16* __restrict__ dst, int n4){
  int i = blockIdx.x * 256 + threadIdx.x;
  int stride = gridDim.x * 256;
  for (; i < n4; i += stride){
    float4 v = ((const float4*)src)[i];
    u16x4 o; o.x = f2bf(v.x); o.y = f2bf(v.y); o.z = f2bf(v.z); o.w = f2bf(v.w);
    ((u16x4*)dst)[i] = o;
  }
}

// concat q_b,k_b,v_b -> one 3072-float bias
__global__ void k_cat3(const float* __restrict__ a, const float* __restrict__ b,
                       const float* __restrict__ c, float* __restrict__ dst){
  int i = blockIdx.x * 256 + threadIdx.x;
  dst[i] = i < 1024 ? a[i] : (i < 2048 ? b[i - 1024] : c[i - 2048]);
}

// ---------------- LayerNorm over C=1024: f32 in -> bf16 out ----------------
__global__ __launch_bounds__(256) void k_ln(const float* __restrict__ x, const float* __restrict__ w,
                                            const float* __restrict__ b, u16* __restrict__ out){
  const int t = threadIdx.x;
  const size_t m = blockIdx.x;
  float4 v = ((const float4*)(x + m * 1024))[t];
  float s  = v.x + v.y + v.z + v.w;
  float s2 = v.x*v.x + v.y*v.y + v.z*v.z + v.w*v.w;
  #pragma unroll
  for (int o = 32; o > 0; o >>= 1){ s += __shfl_down(s, o, 64); s2 += __shfl_down(s2, o, 64); }
  __shared__ float red[8];
  if ((t & 63) == 0){ red[t >> 6] = s; red[4 + (t >> 6)] = s2; }
  __syncthreads();
  s  = red[0] + red[1] + red[2] + red[3];
  s2 = red[4] + red[5] + red[6] + red[7];
  float mu  = s * (1.f / 1024.f);
  float inv = rsqrtf(s2 * (1.f / 1024.f) - mu * mu + 1e-5f);
  float4 wv = ((const float4*)w)[t];
  float4 bv = ((const float4*)b)[t];
  u16x4 o;
  o.x = f2bf((v.x - mu) * inv * wv.x + bv.x);
  o.y = f2bf((v.y - mu) * inv * wv.y + bv.y);
  o.z = f2bf((v.z - mu) * inv * wv.z + bv.z);
  o.w = f2bf((v.w - mu) * inv * wv.w + bv.w);
  ((u16x4*)(out + m * 1024))[t] = o;
}

// ---------------- per-token linear attention ----------------
__global__ __launch_bounds__(256) void k_attn(const u16* __restrict__ qkv, u16* __restrict__ out){
  __shared__ float qe[4][16][68];
  __shared__ float ke[4][16][68];
  __shared__ float sm[4][16][20];
  const int w = threadIdx.x >> 6, lane = threadIdx.x & 63;
  const size_t m = (size_t)blockIdx.x * 4 + w;
  const u16* base = qkv + m * 3072;
  #pragma unroll
  for (int i = 0; i < 8; ++i){
    int idx = i * 64 + lane;
    int h = idx >> 5, c2 = (idx & 31) * 2;
    u32 qv = ((const u32*)base)[idx];
    u32 kv = ((const u32*)base)[512 + idx];
    float2 qf, kf;
    qf.x = elu1(bf2f((u16)(qv & 0xffffu))); qf.y = elu1(bf2f((u16)(qv >> 16)));
    kf.x = elu1(bf2f((u16)(kv & 0xffffu))); kf.y = elu1(bf2f((u16)(kv >> 16)));
    *(float2*)&qe[w][h][c2] = qf;
    *(float2*)&ke[w][h][c2] = kf;
  }
  float vr[16];
  #pragma unroll
  for (int h = 0; h < 16; ++h) vr[h] = bf2f(base[2048 + h * 64 + lane]);
  __syncthreads();
  const int sh = lane >> 2, jb = lane & 3;
  float sacc[4] = {0.f, 0.f, 0.f, 0.f};
  #pragma unroll
  for (int d4 = 0; d4 < 16; ++d4){
    float4 q4 = *(const float4*)&qe[w][sh][d4 * 4];
    #pragma unroll
    for (int j = 0; j < 4; ++j){
      float4 k4 = *(const float4*)&ke[w][4 * jb + j][d4 * 4];
      sacc[j] += q4.x*k4.x + q4.y*k4.y + q4.z*k4.z + q4.w*k4.w;
    }
  }
  #pragma unroll
  for (int j = 0; j < 4; ++j) sm[w][sh][4 * jb + j] = sacc[j];
  float part = sacc[0] + sacc[1] + sacc[2] + sacc[3];
  part += __shfl_xor(part, 1, 64);
  part += __shfl_xor(part, 2, 64);
  if (jb == 0) sm[w][sh][16] = part;
  __syncthreads();
  float acc[16];
  #pragma unroll
  for (int h = 0; h < 16; ++h) acc[h] = 0.f;
  #pragma unroll
  for (int h = 0; h < 16; ++h){
    #pragma unroll
    for (int j4 = 0; j4 < 4; ++j4){
      float4 s4 = *(const float4*)&sm[w][h][j4 * 4];
      acc[h] += s4.x*vr[4*j4] + s4.y*vr[4*j4+1] + s4.z*vr[4*j4+2] + s4.w*vr[4*j4+3];
    }
  }
  u16* ob = out + m * 1024;
  #pragma unroll
  for (int h = 0; h < 16; ++h)
    ob[h * 64 + lane] = f2bf(acc[h] / sm[w][h][16]);
}

// ---------------- 256x256-tile 8-wave bf16 GEMM, 4-phase K-tile schedule ----------------
// C = A(M,K) * W(N,K)^T + bias.  EPI 0: bf16 out  1: f32 = res + v  2: bf16 = gelu(v)  3: f32 += v
template<int Q, int IB, int AE>
__device__ __forceinline__ void quadf(f32x4 (&acc)[8][4], bf16x8 (&a)[AE][2], bf16x8 (&b)[4][2]){
  __builtin_amdgcn_s_setprio(1);
  #pragma unroll
  for (int s = 0; s < 2; ++s)
    #pragma unroll
    for (int i = 0; i < 2; ++i)
      #pragma unroll
      for (int nf = 0; nf < 4; ++nf)
        acc[2*Q+i][nf] = __builtin_amdgcn_mfma_f32_16x16x32_bf16(a[IB+i][s], b[nf][s], acc[2*Q+i][nf], 0, 0, 0);
  __builtin_amdgcn_s_setprio(0);
}

template<int EPI>
__global__ __launch_bounds__(512, 2) void k_gemm(const u16* __restrict__ A, const u16* __restrict__ W,
                                                 const float* __restrict__ bias, const float* __restrict__ res,
                                                 void* __restrict__ outp, int N, int K, int nbn){
  __shared__ alignas(16) char lds[131072];   // buf b: A @ b*65536 (32K), B @ b*65536+32768 (32K)
  const int tid  = threadIdx.x;
  const int lane = tid & 63, wid = tid >> 6;      // 8 waves: 2 (M) x 4 (N)
  const int wr = wid >> 2, wc = wid & 3;
  const int g = lane >> 4, l15 = lane & 15;
  // bijective XCD swizzle (all grids are multiples of 8)
  const int nwg = gridDim.x, bid = blockIdx.x;
  const int swz = (bid & 7) * (nwg >> 3) + (bid >> 3);
  const int m0 = (swz / nbn) * 256, n0 = (swz % nbn) * 256;
  const u16* gA = A + (size_t)m0 * K;
  const u16* gW = W + (size_t)n0 * K;
  const int nt = K >> 6;

  f32x4 acc[8][4];
  #pragma unroll
  for (int i = 0; i < 8; ++i)
    #pragma unroll
    for (int j = 0; j < 4; ++j) acc[i][j] = (f32x4){0.f, 0.f, 0.f, 0.f};

  // stage one 128-row half-tile (16KB): 2 x global_load_lds(16B) per thread.
  // LDS dest linear (wave-uniform base + lane*16); global source chunk-XOR'd so
  // the swizzled ds_reads below see global chunk (4s+g) at LDS chunk (4s+g)^(row&7).
  auto stageA = [&](int b, int kt, int h){
    char* dst = lds + b * 65536 + h * 16384 + wid * 1024;
    const u16* src = gA + (size_t)(h * 128) * K + (kt << 6);
    #pragma unroll
    for (int i = 0; i < 2; ++i){
      int li = i * 512 + tid;
      int r  = li >> 3;
      int ch = (li & 7) ^ (r & 7);
      __builtin_amdgcn_global_load_lds(
        (const __attribute__((address_space(1))) u32*)(src + (size_t)r * K + ch * 8),
        (__attribute__((address_space(3))) u32*)(dst + i * 8192), 16, 0, 0);
    }
  };
  auto stageB = [&](int b, int kt, int h){
    char* dst = lds + b * 65536 + 32768 + h * 16384 + wid * 1024;
    const u16* src = gW + (size_t)(h * 128) * K + (kt << 6);
    #pragma unroll
    for (int i = 0; i < 2; ++i){
      int li = i * 512 + tid;
      int r  = li >> 3;
      int ch = (li & 7) ^ (r & 7);
      __builtin_amdgcn_global_load_lds(
        (const __attribute__((address_space(1))) u32*)(src + (size_t)r * K + ch * 8),
        (__attribute__((address_space(3))) u32*)(dst + i * 8192), 16, 0, 0);
    }
  };

  // ---- prologue: tile0 fully staged, tile1 A-halves in flight ----
  stageA(0, 0, 0); stageA(0, 0, 1); stageB(0, 0, 0); stageB(0, 0, 1);
  if (nt > 1){
    stageA(1, 1, 0); stageA(1, 1, 1);
    asm volatile("s_waitcnt vmcnt(4)" ::: "memory");   // tile0's 4 halves landed
  } else {
    asm volatile("s_waitcnt vmcnt(0)" ::: "memory");
  }
  __builtin_amdgcn_s_barrier();

  for (int t = 0; t < nt; ++t){
    const int c = t & 1;
    const char* Ab = lds + c * 65536;
    const char* Bb = Ab + 32768;
    bf16x8 bfr[4][2], aQ[2][2], aH[4][2];

    // ---- phase 1: read all B frags + A mf{0,1}; stage B-half0(t+1); quad 0 ----
    #pragma unroll
    for (int nf = 0; nf < 4; ++nf)
      #pragma unroll
      for (int s = 0; s < 2; ++s){
        int row = wc * 64 + nf * 16 + l15;
        bfr[nf][s] = *(const bf16x8*)(Bb + row * 128 + (((4 * s + g) ^ (row & 7)) << 4));
      }
    #pragma unroll
    for (int i = 0; i < 2; ++i)
      #pragma unroll
      for (int s = 0; s < 2; ++s){
        int row = wr * 128 + i * 16 + l15;
        aQ[i][s] = *(const bf16x8*)(Ab + row * 128 + (((4 * s + g) ^ (row & 7)) << 4));
      }
    if (t + 1 < nt) stageB(c ^ 1, t + 1, 0);
    __builtin_amdgcn_s_barrier();
    quadf<0, 0>(acc, aQ, bfr);
    __builtin_amdgcn_s_barrier();

    // ---- phase 2: read A mf{2,3} + mf{4..7}; stage B-half1(t+1); quad 1 ----
    #pragma unroll
    for (int i = 0; i < 2; ++i)
      #pragma unroll
      for (int s = 0; s < 2; ++s){
        int row = wr * 128 + (2 + i) * 16 + l15;
        aQ[i][s] = *(const bf16x8*)(Ab + row * 128 + (((4 * s + g) ^ (row & 7)) << 4));
      }
    #pragma unroll
    for (int i = 0; i < 4; ++i)
      #pragma unroll
      for (int s = 0; s < 2; ++s){
        int row = wr * 128 + (4 + i) * 16 + l15;
        aH[i][s] = *(const bf16x8*)(Ab + row * 128 + (((4 * s + g) ^ (row & 7)) << 4));
      }
    if (t + 1 < nt) stageB(c ^ 1, t + 1, 1);
    __builtin_amdgcn_s_barrier();
    quadf<1, 0>(acc, aQ, bfr);
    asm volatile("s_waitcnt lgkmcnt(0)" ::: "memory");  // all our ds_reads of buf c done
    __builtin_amdgcn_s_barrier();                       // -> buf c free for overwrite

    // ---- phase 3: stage A-half0(t+2) into freed buf c; quad 2 (regs) ----
    if (t + 2 < nt) stageA(c, t + 2, 0);
    __builtin_amdgcn_s_barrier();
    quadf<2, 0>(acc, aH, bfr);
    __builtin_amdgcn_s_barrier();

    // ---- phase 4: stage A-half1(t+2); counted vmcnt; quad 3 ----
    if (t + 2 < nt){
      stageA(c, t + 2, 1);
      asm volatile("s_waitcnt vmcnt(4)" ::: "memory");  // 4 newest = t+2's A stages; all of t+1 landed
    } else {
      asm volatile("s_waitcnt vmcnt(0)" ::: "memory");  // tail tiles: drain
    }
    __builtin_amdgcn_s_barrier();
    quadf<3, 2>(acc, aH, bfr);
    __builtin_amdgcn_s_barrier();
  }

  // epilogue: D frag col = lane&15, row = 4*(lane>>4) + r
  #pragma unroll
  for (int mf = 0; mf < 8; ++mf){
    #pragma unroll
    for (int nf = 0; nf < 4; ++nf){
      int row = m0 + wr * 128 + mf * 16 + 4 * g;
      int col = n0 + wc * 64 + nf * 16 + l15;
      float bcol = bias[col];
      #pragma unroll
      for (int r = 0; r < 4; ++r){
        float v = acc[mf][nf][r] + bcol;
        size_t idx = (size_t)(row + r) * N + col;
        if constexpr (EPI == 0){
          ((u16*)outp)[idx] = f2bf(v);
        } else if constexpr (EPI == 1){
          ((float*)outp)[idx] = res[idx] + v;
        } else if constexpr (EPI == 2){
          ((u16*)outp)[idx] = f2bf(gelu_f(v));
        } else {
          float* o = (float*)outp; o[idx] = o[idx] + v;
        }
      }
    }
  }
}

extern "C" void kernel_launch(void* const* d_in, const int* in_sizes, int n_in,
                              void* d_out, int out_size, void* d_ws, size_t ws_size,
                              hipStream_t stream){
  (void)in_sizes; (void)n_in; (void)out_size; (void)ws_size;
  const float* x    = (const float*)d_in[0];
  const float* ln1w = (const float*)d_in[1];
  const float* ln1b = (const float*)d_in[2];
  const float* qw   = (const float*)d_in[3];
  const float* qb   = (const float*)d_in[4];
  const float* kw   = (const float*)d_in[5];
  const float* kb   = (const float*)d_in[6];
  const float* vw   = (const float*)d_in[7];
  const float* vb   = (const float*)d_in[8];
  const float* ow   = (const float*)d_in[9];
  const float* ob   = (const float*)d_in[10];
  const float* ln2w = (const float*)d_in[11];
  const float* ln2b = (const float*)d_in[12];
  const float* fcw  = (const float*)d_in[13];
  const float* fcb  = (const float*)d_in[14];
  const float* pw   = (const float*)d_in[15];
  const float* pb   = (const float*)d_in[16];

  char* ws = (char*)d_ws;
  u16*   WQKV = (u16*)(ws + 0);              // [3072][1024] bf16 (q_w|k_w|v_w)
  u16*   WO   = (u16*)(ws + 6291456);        // [1024][1024]
  u16*   WFC  = (u16*)(ws + 8388608);        // [4096][1024]
  u16*   WPR  = (u16*)(ws + 16777216);       // [1024][4096]
  float* BQ   = (float*)(ws + 25165824);     // [3072]
  u16*   XN   = (u16*)(ws + 25178112);       // [16384][1024] bf16 (xn, reused for xn2)
  u16*   QKV  = (u16*)(ws + 58732544);       // [16384][3072] bf16
  u16*   ATT  = (u16*)(ws + 159395840);      // [16384][1024] bf16
  u16*   H    = QKV;                          // [16384][4096] bf16, reuses QKV+ATT region
  float* OUT  = (float*)d_out;               // x1 intermediate, then final output

  // weight casts (fp32 -> bf16)
  k_cast<<<512, 256, 0, stream>>>(qw, WQKV,           262144);
  k_cast<<<512, 256, 0, stream>>>(kw, WQKV + 1048576, 262144);
  k_cast<<<512, 256, 0, stream>>>(vw, WQKV + 2097152, 262144);
  k_cast<<<512, 256, 0, stream>>>(ow, WO,             262144);
  k_cast<<<1024, 256, 0, stream>>>(fcw, WFC,          1048576);
  k_cast<<<1024, 256, 0, stream>>>(pw,  WPR,          1048576);
  k_cat3<<<12, 256, 0, stream>>>(qb, kb, vb, BQ);

  // ln1 -> fused QKV gemm -> per-token attention -> O gemm (+x residual) -> OUT (x1)
  k_ln<<<16384, 256, 0, stream>>>(x, ln1w, ln1b, XN);
  k_gemm<0><<<64 * 12, 512, 0, stream>>>(XN, WQKV, BQ, nullptr, QKV, 3072, 1024, 12);
  k_attn<<<4096, 256, 0, stream>>>(QKV, ATT);
  k_gemm<1><<<64 * 4, 512, 0, stream>>>(ATT, WO, ob, x, OUT, 1024, 1024, 4);

  // ln2 -> FC gemm (+gelu) -> PROJ gemm (+x1 residual, in place on OUT)
  k_ln<<<16384, 256, 0, stream>>>(OUT, ln2w, ln2b, XN);
  k_gemm<2><<<64 * 16, 512, 0, stream>>>(XN, WFC, fcb, nullptr, H, 4096, 1024, 16);
  k_gemm<3><<<64 * 4, 512, 0, stream>>>(H, WPR, pb, nullptr, OUT, 1024, 4096, 4);
}